// Round 6
// baseline (392.002 us; speedup 1.0000x reference)
//
#include <hip/hip_runtime.h>

typedef unsigned short u16;
typedef __bf16 bf16_t;
typedef bf16_t bf16x8 __attribute__((ext_vector_type(8)));
typedef u16 u16x8 __attribute__((ext_vector_type(8)));
typedef u16 u16x4 __attribute__((ext_vector_type(4)));
typedef float f32x4 __attribute__((ext_vector_type(4)));

#define DEVI __device__ __forceinline__

// B=2, S=1024, E=1024, H=16, DH=64, MAXLEN=2048, table=4095

DEVI u16 f2bf(float f) {
    unsigned u = __builtin_bit_cast(unsigned, f);
    u = (u + 0x7FFFu + ((u >> 16) & 1u)) >> 16;
    return (u16)u;
}
DEVI float bf2f(u16 b) {
    unsigned u = ((unsigned)b) << 16;
    return __builtin_bit_cast(float, u);
}
DEVI f32x4 mfma16(u16x8 a, u16x8 b, f32x4 c) {
    return __builtin_amdgcn_mfma_f32_16x16x32_bf16(
        __builtin_bit_cast(bf16x8, a), __builtin_bit_cast(bf16x8, b), c, 0, 0, 0);
}
// async global->LDS, 16B per lane; LDS dest = base + lane*16 (wave-uniform base)
DEVI void gl2lds(const u16* g, u16* l) {
    __builtin_amdgcn_global_load_lds(
        (__attribute__((address_space(1))) void*)g,
        (__attribute__((address_space(3))) void*)l, 16, 0, 0);
}

// ------- prep: fp32->bf16 cvt (q,k,v,emb) + W transpose, one kernel ---------
__global__ __launch_bounds__(256) void prep_kernel(
    const float* __restrict__ q, const float* __restrict__ k, const float* __restrict__ v,
    const float* __restrict__ emb,
    const float* __restrict__ w0, const float* __restrict__ w1,
    const float* __restrict__ w2, const float* __restrict__ w3,
    u16* __restrict__ xq, u16* __restrict__ xk, u16* __restrict__ xv, u16* __restrict__ embb,
    u16* __restrict__ t0, u16* __restrict__ t1, u16* __restrict__ t2, u16* __restrict__ t3)
{
    const long NQ = 2097152;   // 2*1024*1024
    const long NE = 262080;    // 4095*64
    int t = threadIdx.x;
    if (blockIdx.x < 6400) {
        long i4 = ((long)blockIdx.x * 256 + t) * 4;
        if (i4 < 3 * NQ) {
            int which = (int)(i4 >> 21);
            long off = i4 & (NQ - 1);
            const float* src = which == 0 ? q : (which == 1 ? k : v);
            u16* dst = which == 0 ? xq : (which == 1 ? xk : xv);
            float4 f = *(const float4*)(src + off);
            ushort4 o; o.x = f2bf(f.x); o.y = f2bf(f.y); o.z = f2bf(f.z); o.w = f2bf(f.w);
            *(ushort4*)(dst + off) = o;
        } else {
            long off = i4 - 3 * NQ;
            if (off < NE) {
                float4 f = *(const float4*)(emb + off);
                ushort4 o; o.x = f2bf(f.x); o.y = f2bf(f.y); o.z = f2bf(f.z); o.w = f2bf(f.w);
                *(ushort4*)(embb + off) = o;
            }
        }
    } else {
        int bx = blockIdx.x - 6400;          // 0..1023
        int z = bx >> 8;
        int rem = bx & 255;
        const float* W = z == 0 ? w0 : (z == 1 ? w1 : (z == 2 ? w2 : w3));
        u16* T = z == 0 ? t0 : (z == 1 ? t1 : (z == 2 ? t2 : t3));
        __shared__ float tile[64][65];
        int n0 = (rem & 15) * 64, k0 = (rem >> 4) * 64;
        int tx = t & 63, ty = t >> 6;
        for (int r = ty; r < 64; r += 4)
            tile[r][tx] = W[(long)(k0 + r) * 1024 + n0 + tx];
        __syncthreads();
        for (int r = ty; r < 64; r += 4)
            T[(long)(n0 + r) * 1024 + k0 + tx] = f2bf(tile[tx][r]);
    }
}

// ---------------- bf16 MFMA GEMM, global_load_lds staging -------------------
// C[M][N=1024] tile (MT*32) x 128; A[M][1024], WT[N][1024] (both row-major K)
// mode 0: q-proj ((acc+b)*0.125 -> qb [B,H,S,DH]); 1: k-proj -> kb; 2: v-proj -> vT [B,H,DH,S];
// mode 3: out-proj -> fp32 [M][N]
template<int MT>
__global__ __launch_bounds__(256) void gemm_kernel(
    const u16* __restrict__ A0, const u16* __restrict__ A1, const u16* __restrict__ A2,
    const u16* __restrict__ W0, const u16* __restrict__ W1, const u16* __restrict__ W2,
    const float* __restrict__ bias0, const float* __restrict__ bias1, const float* __restrict__ bias2,
    u16* __restrict__ o0, u16* __restrict__ o1, u16* __restrict__ o2,
    float* __restrict__ ofp, int mode_base)
{
    int z = blockIdx.z;
    int mode = mode_base + z;
    const u16* A = z == 0 ? A0 : (z == 1 ? A1 : A2);
    const u16* W = z == 0 ? W0 : (z == 1 ? W1 : W2);
    const float* bias = z == 0 ? bias0 : (z == 1 ? bias1 : bias2);
    u16* ob = z == 0 ? o0 : (z == 1 ? o1 : o2);

    constexpr int MROWS = MT * 32;
    __shared__ u16 la[MROWS * 32];
    __shared__ u16 lw[128 * 32];

    int m0 = blockIdx.y * MROWS, n0 = blockIdx.x * 128;
    int t = threadIdx.x, lane = t & 63, wid = t >> 6;
    int l15 = lane & 15, quad = lane >> 4;
    int wm = (wid >> 1) * (MT * 16), wn = (wid & 1) * 64;
    int sr = lane >> 2, sp = lane & 3;   // staging: 16 rows x 4 chunks per instr

    f32x4 acc[MT][4] = {};

    for (int k0 = 0; k0 < 1024; k0 += 32) {
        __syncthreads();
#pragma unroll
        for (int q = 0; q < MT / 2; q++) {
            int r = wid * (MT * 8) + q * 16 + sr;
            int c = sp ^ ((r >> 1) & 3);
            gl2lds(A + (long)(m0 + r) * 1024 + k0 + c * 8, la + (wid * (MT * 8) + q * 16) * 32);
        }
#pragma unroll
        for (int q = 0; q < 2; q++) {
            int r = wid * 32 + q * 16 + sr;
            int c = sp ^ ((r >> 1) & 3);
            gl2lds(W + (long)(n0 + r) * 1024 + k0 + c * 8, lw + (wid * 32 + q * 16) * 32);
        }
        __syncthreads();
        u16x8 af[MT], bfr[4];
#pragma unroll
        for (int mt = 0; mt < MT; mt++) {
            int r = wm + mt * 16 + l15;
            af[mt] = *(const u16x8*)&la[r * 32 + ((quad ^ ((r >> 1) & 3)) * 8)];
        }
#pragma unroll
        for (int nt = 0; nt < 4; nt++) {
            int r = wn + nt * 16 + l15;
            bfr[nt] = *(const u16x8*)&lw[r * 32 + ((quad ^ ((r >> 1) & 3)) * 8)];
        }
#pragma unroll
        for (int mt = 0; mt < MT; mt++)
#pragma unroll
            for (int nt = 0; nt < 4; nt++)
                acc[mt][nt] = mfma16(af[mt], bfr[nt], acc[mt][nt]);
    }

#pragma unroll
    for (int mt = 0; mt < MT; mt++)
#pragma unroll
        for (int nt = 0; nt < 4; nt++)
#pragma unroll
            for (int reg = 0; reg < 4; reg++) {
                int gm = m0 + wm + mt * 16 + quad * 4 + reg;   // C row = quad*4+reg
                int gn = n0 + wn + nt * 16 + l15;              // C col = lane&15
                float val = acc[mt][nt][reg] + bias[gn];
                if (mode == 0) {
                    val *= 0.125f;   // 1/sqrt(DH)
                    long o = ((long)((gm >> 10) * 16 + (gn >> 6)) << 16) + ((gm & 1023) << 6) + (gn & 63);
                    ob[o] = f2bf(val);
                } else if (mode == 1) {
                    long o = ((long)((gm >> 10) * 16 + (gn >> 6)) << 16) + ((gm & 1023) << 6) + (gn & 63);
                    ob[o] = f2bf(val);
                } else if (mode == 2) {
                    long o = ((long)((gm >> 10) * 16 + (gn >> 6)) << 16) + ((long)(gn & 63) << 10) + (gm & 1023);
                    ob[o] = f2bf(val);
                } else {
                    ofp[(long)gm * 1024 + gn] = val;
                }
            }
}

// ---------------- Gw skewed GEMM, TRANSPOSED for vector stores --------------
// Gw[u][w] = q[u] . emb[1024 + i0 + w], w in [0,1040), i0 = (u & 1023) & ~15.
// Flash gathers: branch1 (c=ii-jj>=0): Gw[ii][c + (ii&15)]
//                branch2 (c<=-2):      Gw[ii+1][c + 1025 + ((ii+1)&15)]
//                diag (c==-1): 0       (+ rpb[c+2047] always, added in flash)
__global__ __launch_bounds__(256, 8) void gc_kernel(
    const u16* __restrict__ qb, const u16* __restrict__ embb, u16* __restrict__ Gw)
{
    int u0 = blockIdx.x * 16;
    int i0 = u0 & 1023;
    int t = threadIdx.x, lane = t & 63, wid = t >> 6;
    int l15 = lane & 15, quad = lane >> 4;

    long qoff = (long)(u0 + l15) * 64 + quad * 8;
    u16x8 bq0 = *(const u16x8*)&qb[qoff];
    u16x8 bq1 = *(const u16x8*)&qb[qoff + 32];

    u16* orow = Gw + (long)(u0 + l15) * 1040 + quad * 4;
    const u16* ebase0 = embb + (long)(1024 + i0 + l15) * 64 + quad * 8;

    for (int tt = wid; tt < 65; tt += 4) {
        const u16* ep = ebase0 + (long)tt * 1024;   // tt*16 rows * 64
        u16x8 a0 = *(const u16x8*)ep;
        u16x8 a1 = *(const u16x8*)(ep + 32);
        f32x4 c = {};
        c = mfma16(a0, bq0, c);
        c = mfma16(a1, bq1, c);
        u16x4 o;
        o[0] = f2bf(c[0]); o[1] = f2bf(c[1]); o[2] = f2bf(c[2]); o[3] = f2bf(c[3]);
        *(u16x4*)(orow + tt * 16) = o;   // 8 B aligned: (row*1040 + 4k)*2
    }
}

// ---------------- flash attention (j-split x4, bf16 partial O) --------------
// LDS tiles [64 rows][64 u16], chunk (8 u16) swizzle: pos p = c ^ (row&7)
__global__ __launch_bounds__(256, 5) void flash_kernel(
    const u16* __restrict__ qb, const u16* __restrict__ kb, const u16* __restrict__ vT,
    const u16* __restrict__ Gw, const float* __restrict__ rpb,
    u16* __restrict__ Po, float* __restrict__ Pm, float* __restrict__ Pl)
{
    int itile = blockIdx.x;        // 0..15
    int bh = blockIdx.y;           // 0..31
    int js = blockIdx.z;           // 0..3
    int t = threadIdx.x, lane = t & 63, wid = t >> 6;
    int l15 = lane & 15, quad = lane >> 4;
    int i0 = itile * 64;
    int i0w = i0 + wid * 16;

    __shared__ u16 lds_k[64 * 64];     // [j][d]
    __shared__ u16 lds_v[64 * 64];     // [d][j]
    __shared__ u16 lds_p[4][16][72];   // per-wave P
    __shared__ float lrpb[320];

    int c_lo = i0 - js * 256 - 255;
    // FIX (R5 bug): strided fill — 256 threads must cover all 320 entries;
    // previously lrpb[256..318] stayed poisoned and corrupted every block's scores.
    for (int idx = t; idx < 320; idx += 256)
        lrpb[idx] = rpb[c_lo + 2047 + idx];

    int sr8 = lane >> 3, sp8 = lane & 7;   // staging: 8 rows x 8 chunks per instr

    u16x8 aq[2];
    {
        long qoff = ((long)(bh * 1024) + i0w + l15) * 64 + quad * 8;
        aq[0] = *(const u16x8*)&qb[qoff];
        aq[1] = *(const u16x8*)&qb[qoff + 32];
    }
    float m_r[4], l_r[4];
    f32x4 o_acc[4] = {};
#pragma unroll
    for (int r = 0; r < 4; r++) { m_r[r] = -1e30f; l_r[r] = 0.f; }

    const u16* kbase = kb + (long)bh * 65536;
    const u16* vbase = vT + (long)bh * 65536;
    const u16* gwb = Gw + (long)bh * 1024 * 1040;

    for (int jt = 0; jt < 4; jt++) {
        int j0 = js * 256 + jt * 64;
        __syncthreads();
#pragma unroll
        for (int q = 0; q < 2; q++) {
            int r = wid * 16 + q * 8 + sr8;
            int c = sp8 ^ (r & 7);
            gl2lds(kbase + (long)(j0 + r) * 64 + c * 8, lds_k + (wid * 16 + q * 8) * 64);
            gl2lds(vbase + (long)r * 1024 + j0 + c * 8, lds_v + (wid * 16 + q * 8) * 64);
        }
        __syncthreads();

        // S = q @ k^T  (16 rows x 64 cols per wave)
        f32x4 s_acc[4];
#pragma unroll
        for (int nt = 0; nt < 4; nt++) {
            int r = nt * 16 + l15;
            u16x8 b0 = *(const u16x8*)&lds_k[r * 64 + ((quad ^ (r & 7)) * 8)];
            u16x8 b1 = *(const u16x8*)&lds_k[r * 64 + (((quad + 4) ^ (r & 7)) * 8)];
            f32x4 c = {};
            c = mfma16(aq[0], b0, c);
            c = mfma16(aq[1], b1, c);
            s_acc[nt] = c;
        }

        // + rel (Gw skew-gather) + rpb (LDS)
#pragma unroll
        for (int nt = 0; nt < 4; nt++) {
            int jj = j0 + nt * 16 + l15;
#pragma unroll
            for (int reg = 0; reg < 4; reg++) {
                int q4r = quad * 4 + reg;
                int ii = i0w + q4r;
                int c = ii - jj;
                long a1 = (long)ii * 1040 + c + (ii & 15);                      // branch1
                long a2 = (long)(ii + 1) * 1040 + c + 1025 + ((ii + 1) & 15);   // branch2
                long ga = (c >= 0) ? a1 : a2;
                float gval = (c == -1) ? 0.f : bf2f(gwb[ga]);
                s_acc[nt][reg] += gval + lrpb[c - c_lo];
            }
        }

        // online softmax (rows at quad*4+reg, 16 lanes per row-group)
#pragma unroll
        for (int reg = 0; reg < 4; reg++) {
            float mx = fmaxf(fmaxf(s_acc[0][reg], s_acc[1][reg]), fmaxf(s_acc[2][reg], s_acc[3][reg]));
            for (int off = 1; off < 16; off <<= 1) mx = fmaxf(mx, __shfl_xor(mx, off, 64));
            float mnew = fmaxf(m_r[reg], mx);
            float alpha = __expf(m_r[reg] - mnew);
            float rs = 0.f;
#pragma unroll
            for (int nt = 0; nt < 4; nt++) {
                float p = __expf(s_acc[nt][reg] - mnew);
                s_acc[nt][reg] = p;
                rs += p;
            }
            for (int off = 1; off < 16; off <<= 1) rs += __shfl_xor(rs, off, 64);
            l_r[reg] = l_r[reg] * alpha + rs;
            m_r[reg] = mnew;
#pragma unroll
            for (int dt = 0; dt < 4; dt++) o_acc[dt][reg] *= alpha;
        }

        // P: C-layout -> LDS -> A-layout
#pragma unroll
        for (int nt = 0; nt < 4; nt++)
#pragma unroll
            for (int reg = 0; reg < 4; reg++)
                lds_p[wid][quad * 4 + reg][nt * 16 + l15] = f2bf(s_acc[nt][reg]);

        u16x8 pf0 = *(const u16x8*)&lds_p[wid][l15][quad * 8];
        u16x8 pf1 = *(const u16x8*)&lds_p[wid][l15][quad * 8 + 32];
#pragma unroll
        for (int dt = 0; dt < 4; dt++) {
            int r = dt * 16 + l15;
            u16x8 v0 = *(const u16x8*)&lds_v[r * 64 + ((quad ^ (r & 7)) * 8)];
            u16x8 v1 = *(const u16x8*)&lds_v[r * 64 + (((quad + 4) ^ (r & 7)) * 8)];
            o_acc[dt] = mfma16(pf0, v0, o_acc[dt]);
            o_acc[dt] = mfma16(pf1, v1, o_acc[dt]);
        }
    }

    int blk = (js * 32 + bh) * 16 + itile;
    u16* PoB = Po + (long)blk * 4096;
#pragma unroll
    for (int dt = 0; dt < 4; dt++)
#pragma unroll
        for (int reg = 0; reg < 4; reg++) {
            int rr = wid * 16 + quad * 4 + reg;
            PoB[rr * 64 + dt * 16 + l15] = f2bf(o_acc[dt][reg]);
        }
    if (l15 == 0) {
#pragma unroll
        for (int reg = 0; reg < 4; reg++) {
            int rr = wid * 16 + quad * 4 + reg;
            Pm[blk * 64 + rr] = m_r[reg];
            Pl[blk * 64 + rr] = l_r[reg];
        }
    }
}

// ---------------- combine the 4 j-partials -> attn (bf16 [B,S,E]) -----------
__global__ __launch_bounds__(256) void combine_kernel(
    const u16* __restrict__ Po, const float* __restrict__ Pm, const float* __restrict__ Pl,
    u16* __restrict__ attn)
{
    int itile = blockIdx.x, bh = blockIdx.y;
    int t = threadIdx.x;
    int c = t & 63, rg = t >> 6;
    int b = bh >> 4, h = bh & 15;
    int blks[4];
#pragma unroll
    for (int s = 0; s < 4; s++) blks[s] = (s * 32 + bh) * 16 + itile;
    for (int rr = rg; rr < 64; rr += 4) {
        float m[4], lv[4];
        float mm = -1e30f;
#pragma unroll
        for (int s = 0; s < 4; s++) { m[s] = Pm[blks[s] * 64 + rr]; mm = fmaxf(mm, m[s]); }
        float l = 0.f, o = 0.f;
#pragma unroll
        for (int s = 0; s < 4; s++) {
            float e = __expf(m[s] - mm);
            lv[s] = Pl[blks[s] * 64 + rr] * e;
            l += lv[s];
            o += bf2f(Po[(long)blks[s] * 4096 + rr * 64 + c]) * e;
        }
        int ii = itile * 64 + rr;
        attn[((long)(b * 1024 + ii)) * 1024 + h * 64 + c] = f2bf(o / l);
    }
}

// ---------------------------------------------------------------------------
extern "C" void kernel_launch(void* const* d_in, const int* in_sizes, int n_in,
                              void* d_out, int out_size, void* d_ws, size_t ws_size,
                              hipStream_t stream)
{
    const float* query = (const float*)d_in[0];
    const float* key_  = (const float*)d_in[1];
    const float* value = (const float*)d_in[2];
    const float* Wq = (const float*)d_in[3];
    const float* bq = (const float*)d_in[4];
    const float* Wk = (const float*)d_in[5];
    const float* bk = (const float*)d_in[6];
    const float* Wv = (const float*)d_in[7];
    const float* bv = (const float*)d_in[8];
    const float* Wo = (const float*)d_in[9];
    const float* bo = (const float*)d_in[10];
    const float* emb = (const float*)d_in[11];
    const float* rpb = (const float*)d_in[12];

    char* ws = (char*)d_ws;
    u16* xq   = (u16*)(ws + 0);          // 4 MB   (dead after QKV gemm)
    u16* xk   = (u16*)(ws + 4194304);    // 4 MB   (dead after QKV gemm)
    u16* xv   = (u16*)(ws + 8388608);    // 4 MB   (dead after QKV gemm)
    u16* WqT  = (u16*)(ws + 12582912);   // 2 MB   (dead after QKV gemm)
    u16* WkT  = (u16*)(ws + 14680064);   // 2 MB   (dead after QKV gemm)
    u16* WvT  = (u16*)(ws + 16777216);   // 2 MB   (dead after QKV gemm)
    u16* embb = (u16*)(ws + 18874368);   // 512 KB (dead after gc)
    u16* WoT  = (u16*)(ws + 19398656);   // 2 MB   (live till final gemm)
    u16* qb   = (u16*)(ws + 21495808);   // 4 MB   (dead after flash)
    u16* kb   = (u16*)(ws + 25690112);   // 4 MB
    u16* vT   = (u16*)(ws + 29884416);   // 4 MB
    u16* Gw   = (u16*)(ws + 34078720);   // 32768*1040*2 = 68.16 MB -> ends ~102.2 MB
    // overlays (regions dead by the time these are written):
    u16*   Po = (u16*)(ws + 0);            // 16 MB bf16 partials over xq/xk/xv/WqT/WkT
    float* Pm = (float*)(ws + 16777216);   // 512 KB over WvT
    float* Pl = (float*)(ws + 17301504);   // 512 KB over WvT (dead)
    u16* attn = (u16*)(ws + 21495808);     // 4 MB over qb

    prep_kernel<<<7424, 256, 0, stream>>>(query, key_, value, emb, Wq, Wk, Wv, Wo,
                                          xq, xk, xv, embb, WqT, WkT, WvT, WoT);
    gemm_kernel<4><<<dim3(8, 16, 3), 256, 0, stream>>>(xq, xk, xv, WqT, WkT, WvT,
                                                       bq, bk, bv, qb, kb, vT, nullptr, 0);
    gc_kernel<<<2048, 256, 0, stream>>>(qb, embb, Gw);
    flash_kernel<<<dim3(16, 32, 4), 256, 0, stream>>>(qb, kb, vT, Gw, rpb, Po, Pm, Pl);
    combine_kernel<<<dim3(16, 32), 256, 0, stream>>>(Po, Pm, Pl, attn);
    gemm_kernel<2><<<dim3(8, 32, 1), 256, 0, stream>>>(attn, nullptr, nullptr, WoT, nullptr, nullptr,
                                                       bo, nullptr, nullptr,
                                                       nullptr, nullptr, nullptr, (float*)d_out, 3);
}

// Round 7
// 274.411 us; speedup vs baseline: 1.4285x; 1.4285x over previous
//
#include <hip/hip_runtime.h>

typedef unsigned short u16;
typedef __bf16 bf16_t;
typedef bf16_t bf16x8 __attribute__((ext_vector_type(8)));
typedef u16 u16x8 __attribute__((ext_vector_type(8)));
typedef u16 u16x4 __attribute__((ext_vector_type(4)));
typedef float f32x4 __attribute__((ext_vector_type(4)));

#define DEVI __device__ __forceinline__

// B=2, S=1024, E=1024, H=16, DH=64, MAXLEN=2048, table=4095

DEVI u16 f2bf(float f) {
    unsigned u = __builtin_bit_cast(unsigned, f);
    u = (u + 0x7FFFu + ((u >> 16) & 1u)) >> 16;
    return (u16)u;
}
DEVI float bf2f(u16 b) {
    unsigned u = ((unsigned)b) << 16;
    return __builtin_bit_cast(float, u);
}
DEVI f32x4 mfma16(u16x8 a, u16x8 b, f32x4 c) {
    return __builtin_amdgcn_mfma_f32_16x16x32_bf16(
        __builtin_bit_cast(bf16x8, a), __builtin_bit_cast(bf16x8, b), c, 0, 0, 0);
}
// async global->LDS, 16B per lane; LDS dest = base + lane*16 (wave-uniform base)
DEVI void gl2lds(const u16* g, u16* l) {
    __builtin_amdgcn_global_load_lds(
        (__attribute__((address_space(1))) void*)g,
        (__attribute__((address_space(3))) void*)l, 16, 0, 0);
}

// ------- prep: fp32->bf16 cvt (q,k,v,emb) + W transpose, one kernel ---------
__global__ __launch_bounds__(256) void prep_kernel(
    const float* __restrict__ q, const float* __restrict__ k, const float* __restrict__ v,
    const float* __restrict__ emb,
    const float* __restrict__ w0, const float* __restrict__ w1,
    const float* __restrict__ w2, const float* __restrict__ w3,
    u16* __restrict__ xq, u16* __restrict__ xk, u16* __restrict__ xv, u16* __restrict__ embb,
    u16* __restrict__ t0, u16* __restrict__ t1, u16* __restrict__ t2, u16* __restrict__ t3)
{
    const long NQ = 2097152;   // 2*1024*1024
    const long NE = 262080;    // 4095*64
    int t = threadIdx.x;
    if (blockIdx.x < 6400) {
        long i4 = ((long)blockIdx.x * 256 + t) * 4;
        if (i4 < 3 * NQ) {
            int which = (int)(i4 >> 21);
            long off = i4 & (NQ - 1);
            const float* src = which == 0 ? q : (which == 1 ? k : v);
            u16* dst = which == 0 ? xq : (which == 1 ? xk : xv);
            float4 f = *(const float4*)(src + off);
            ushort4 o; o.x = f2bf(f.x); o.y = f2bf(f.y); o.z = f2bf(f.z); o.w = f2bf(f.w);
            *(ushort4*)(dst + off) = o;
        } else {
            long off = i4 - 3 * NQ;
            if (off < NE) {
                float4 f = *(const float4*)(emb + off);
                ushort4 o; o.x = f2bf(f.x); o.y = f2bf(f.y); o.z = f2bf(f.z); o.w = f2bf(f.w);
                *(ushort4*)(embb + off) = o;
            }
        }
    } else {
        int bx = blockIdx.x - 6400;          // 0..1023
        int z = bx >> 8;
        int rem = bx & 255;
        const float* W = z == 0 ? w0 : (z == 1 ? w1 : (z == 2 ? w2 : w3));
        u16* T = z == 0 ? t0 : (z == 1 ? t1 : (z == 2 ? t2 : t3));
        __shared__ float tile[64][65];
        int n0 = (rem & 15) * 64, k0 = (rem >> 4) * 64;
        int tx = t & 63, ty = t >> 6;
        for (int r = ty; r < 64; r += 4)
            tile[r][tx] = W[(long)(k0 + r) * 1024 + n0 + tx];
        __syncthreads();
        for (int r = ty; r < 64; r += 4)
            T[(long)(n0 + r) * 1024 + k0 + tx] = f2bf(tile[tx][r]);
    }
}

// ---------------- bf16 MFMA GEMM, global_load_lds staging -------------------
// mode 0: q-proj ((acc+b)*0.125 -> qb [B,H,S,DH]); 1: k-proj -> kb; 2: v-proj -> vT [B,H,DH,S];
// mode 3: out-proj -> fp32 [M][N]
template<int MT>
__global__ __launch_bounds__(256) void gemm_kernel(
    const u16* __restrict__ A0, const u16* __restrict__ A1, const u16* __restrict__ A2,
    const u16* __restrict__ W0, const u16* __restrict__ W1, const u16* __restrict__ W2,
    const float* __restrict__ bias0, const float* __restrict__ bias1, const float* __restrict__ bias2,
    u16* __restrict__ o0, u16* __restrict__ o1, u16* __restrict__ o2,
    float* __restrict__ ofp, int mode_base)
{
    int z = blockIdx.z;
    int mode = mode_base + z;
    const u16* A = z == 0 ? A0 : (z == 1 ? A1 : A2);
    const u16* W = z == 0 ? W0 : (z == 1 ? W1 : W2);
    const float* bias = z == 0 ? bias0 : (z == 1 ? bias1 : bias2);
    u16* ob = z == 0 ? o0 : (z == 1 ? o1 : o2);

    constexpr int MROWS = MT * 32;
    __shared__ u16 la[MROWS * 32];
    __shared__ u16 lw[128 * 32];

    int m0 = blockIdx.y * MROWS, n0 = blockIdx.x * 128;
    int t = threadIdx.x, lane = t & 63, wid = t >> 6;
    int l15 = lane & 15, quad = lane >> 4;
    int wm = (wid >> 1) * (MT * 16), wn = (wid & 1) * 64;
    int sr = lane >> 2, sp = lane & 3;   // staging: 16 rows x 4 chunks per instr

    f32x4 acc[MT][4] = {};

    for (int k0 = 0; k0 < 1024; k0 += 32) {
        __syncthreads();
#pragma unroll
        for (int q = 0; q < MT / 2; q++) {
            int r = wid * (MT * 8) + q * 16 + sr;
            int c = sp ^ ((r >> 1) & 3);
            gl2lds(A + (long)(m0 + r) * 1024 + k0 + c * 8, la + (wid * (MT * 8) + q * 16) * 32);
        }
#pragma unroll
        for (int q = 0; q < 2; q++) {
            int r = wid * 32 + q * 16 + sr;
            int c = sp ^ ((r >> 1) & 3);
            gl2lds(W + (long)(n0 + r) * 1024 + k0 + c * 8, lw + (wid * 32 + q * 16) * 32);
        }
        __syncthreads();
        u16x8 af[MT], bfr[4];
#pragma unroll
        for (int mt = 0; mt < MT; mt++) {
            int r = wm + mt * 16 + l15;
            af[mt] = *(const u16x8*)&la[r * 32 + ((quad ^ ((r >> 1) & 3)) * 8)];
        }
#pragma unroll
        for (int nt = 0; nt < 4; nt++) {
            int r = wn + nt * 16 + l15;
            bfr[nt] = *(const u16x8*)&lw[r * 32 + ((quad ^ ((r >> 1) & 3)) * 8)];
        }
#pragma unroll
        for (int mt = 0; mt < MT; mt++)
#pragma unroll
            for (int nt = 0; nt < 4; nt++)
                acc[mt][nt] = mfma16(af[mt], bfr[nt], acc[mt][nt]);
    }

#pragma unroll
    for (int mt = 0; mt < MT; mt++)
#pragma unroll
        for (int nt = 0; nt < 4; nt++)
#pragma unroll
            for (int reg = 0; reg < 4; reg++) {
                int gm = m0 + wm + mt * 16 + quad * 4 + reg;   // C row = quad*4+reg
                int gn = n0 + wn + nt * 16 + l15;              // C col = lane&15
                float val = acc[mt][nt][reg] + bias[gn];
                if (mode == 0) {
                    val *= 0.125f;   // 1/sqrt(DH)
                    long o = ((long)((gm >> 10) * 16 + (gn >> 6)) << 16) + ((gm & 1023) << 6) + (gn & 63);
                    ob[o] = f2bf(val);
                } else if (mode == 1) {
                    long o = ((long)((gm >> 10) * 16 + (gn >> 6)) << 16) + ((gm & 1023) << 6) + (gn & 63);
                    ob[o] = f2bf(val);
                } else if (mode == 2) {
                    long o = ((long)((gm >> 10) * 16 + (gn >> 6)) << 16) + ((long)(gn & 63) << 10) + (gm & 1023);
                    ob[o] = f2bf(val);
                } else {
                    ofp[(long)gm * 1024 + gn] = val;
                }
            }
}

// ---------------- skew: fused Gw-strip MFMA -> LDS -> Brel2 (rel+rpb) -------
// Per 16-row strip u0..u0+15 (block), phase A computes (transposed MFMA):
//   Lg[r][w] = bf16( q[u0+r] . emb[1024 + i0 + w] ),  w in [0,1040), i0 = u0 & 1023
// (C/D row quad*4+e = w-local, col l15 = r -> aligned 8B ds_write_b64, no scatter.)
// Phase B emits Brel2[u][j] = rel + rpb with contiguous u16x8 stores:
//   j <= i   : Lg[rr][(i&15) + (i-j)]                       (branch1)
//   j == i+1 : 0                                            (diag)
//   j >= i+2 : Lg[rr+1][((i+1)&15) + (i-j) + 1025]          (branch2, source row u+1)
// Strip edges: row u0-1 gets only its branch2 part here (branch1 written by block-1
// as its row 15); row u0+15 gets only branch1+diag (branch2 by block+1 as row -1).
__global__ __launch_bounds__(256, 4) void skew_kernel(
    const u16* __restrict__ qb, const u16* __restrict__ embb,
    const float* __restrict__ rpb, u16* __restrict__ Brel2)
{
    __shared__ u16 Lg[16 * 1044];    // stride 1044 u16 (8B-mult, bank-spread)
    __shared__ float lrpb[1040];     // rpb window, idx = c - i0 + 1024

    int u0 = blockIdx.x * 16;
    int i0 = u0 & 1023;
    int t = threadIdx.x, lane = t & 63, wid = t >> 6;
    int l15 = lane & 15, quad = lane >> 4;

    for (int idx = t; idx < 1040; idx += 256)
        lrpb[idx] = rpb[i0 + 1023 + idx];

    // Phase A
    long qoff = (long)(u0 + l15) * 64 + quad * 8;
    u16x8 bq0 = *(const u16x8*)&qb[qoff];
    u16x8 bq1 = *(const u16x8*)&qb[qoff + 32];
    const u16* ebase0 = embb + (long)(1024 + i0 + l15) * 64 + quad * 8;
    for (int tt = wid; tt < 65; tt += 4) {
        const u16* ep = ebase0 + (long)tt * 1024;
        u16x8 a0 = *(const u16x8*)ep;
        u16x8 a1 = *(const u16x8*)(ep + 32);
        f32x4 c = {};
        c = mfma16(a0, bq0, c);
        c = mfma16(a1, bq1, c);
        u16x4 o;
        o[0] = f2bf(c[0]); o[1] = f2bf(c[1]); o[2] = f2bf(c[2]); o[3] = f2bf(c[3]);
        *(u16x4*)&Lg[l15 * 1044 + tt * 16 + quad * 4] = o;
    }
    __syncthreads();

    // Phase B: 17 logical rows (rr=-1..15) x 128 chunks of 8
    for (int slot = t; slot < 2176; slot += 256) {
        int rr = (slot >> 7) - 1;
        int j0 = (slot & 127) * 8;
        int up = u0 + rr;
        if (up < 0) continue;
        int i = up & 1023;
        if (rr == -1 && j0 + 7 < i + 2) continue;    // row -1: only branch2 part
        if (rr == 15 && j0 > i + 1) continue;        // row 15: only branch1+diag
        int r1 = i & 15;
        int r2 = (i + 1) & 15;
        u16* outp = Brel2 + ((long)up << 10) + j0;
        int cbase = i - j0;
        if (rr >= 0 && j0 + 7 <= i) {
            const u16* lrow = &Lg[rr * 1044];
            u16x8 o;
#pragma unroll
            for (int e = 0; e < 8; e++) {
                int c = cbase - e;
                o[e] = f2bf(bf2f(lrow[r1 + c]) + lrpb[c - i0 + 1024]);
            }
            *(u16x8*)outp = o;
        } else if (rr <= 14 && j0 >= i + 2) {
            const u16* lrow = &Lg[(rr + 1) * 1044];
            u16x8 o;
#pragma unroll
            for (int e = 0; e < 8; e++) {
                int c = cbase - e;
                o[e] = f2bf(bf2f(lrow[r2 + c + 1025]) + lrpb[c - i0 + 1024]);
            }
            *(u16x8*)outp = o;
        } else {
            // mixed chunk (diag crossing or strip edge): element-wise, ownership-masked
#pragma unroll
            for (int e = 0; e < 8; e++) {
                int j = j0 + e;
                int c = i - j;
                bool mine = (rr >= 0 && rr <= 14) ||
                            (rr == 15 && j <= i + 1) ||
                            (rr == -1 && j >= i + 2);
                if (!mine) continue;
                float v;
                if (c >= 0)       v = bf2f(Lg[rr * 1044 + r1 + c]);
                else if (c == -1) v = 0.f;
                else              v = bf2f(Lg[(rr + 1) * 1044 + r2 + c + 1025]);
                outp[e] = f2bf(v + lrpb[c - i0 + 1024]);
            }
        }
    }
}

// ---------------- flash attention (R2 structure, XCD-swizzled 1-D grid) -----
// js x2 split; Brel2 read branch-free & coalesced; f32 partials.
__global__ __launch_bounds__(256, 4) void flash_kernel(
    const u16* __restrict__ qb, const u16* __restrict__ kb, const u16* __restrict__ vT,
    const u16* __restrict__ Brel2,
    float* __restrict__ Po, float* __restrict__ Pm, float* __restrict__ Pl)
{
    // XCD swizzle: blocks b with b%8==xcd get bh in {4*xcd .. 4*xcd+3} so each
    // bh's K/V/Brel2 stays in one XCD's L2.
    int b = blockIdx.x;                 // 0..1023
    int xcd = b & 7;
    int idx = b >> 3;                   // 0..127
    int bh = xcd * 4 + (idx >> 5);      // 0..31
    int sub = idx & 31;
    int itile = sub & 15;               // 0..15
    int js = sub >> 4;                  // 0..1

    int t = threadIdx.x, lane = t & 63, wid = t >> 6;
    int l15 = lane & 15, quad = lane >> 4;
    int i0w = itile * 64 + wid * 16;

    __shared__ u16 lds_k[64 * 64];     // [j][d]
    __shared__ u16 lds_v[64 * 64];     // [d][j]
    __shared__ u16 lds_p[4][16][72];   // per-wave P

    int sr8 = lane >> 3, sp8 = lane & 7;   // staging: 8 rows x 8 chunks per instr

    u16x8 aq[2];
    {
        long qoff = ((long)(bh * 1024) + i0w + l15) * 64 + quad * 8;
        aq[0] = *(const u16x8*)&qb[qoff];
        aq[1] = *(const u16x8*)&qb[qoff + 32];
    }
    float m_r[4], l_r[4];
    f32x4 o_acc[4] = {};
#pragma unroll
    for (int r = 0; r < 4; r++) { m_r[r] = -1e30f; l_r[r] = 0.f; }

    const u16* kbase = kb + (long)bh * 65536;
    const u16* vbase = vT + (long)bh * 65536;
    const u16* bbase = Brel2 + ((long)bh << 20);

    for (int jt = 0; jt < 8; jt++) {
        int j0 = js * 512 + jt * 64;
        __syncthreads();
#pragma unroll
        for (int q = 0; q < 2; q++) {
            int r = wid * 16 + q * 8 + sr8;
            int c = sp8 ^ (r & 7);
            gl2lds(kbase + (long)(j0 + r) * 64 + c * 8, lds_k + (wid * 16 + q * 8) * 64);
            gl2lds(vbase + (long)r * 1024 + j0 + c * 8, lds_v + (wid * 16 + q * 8) * 64);
        }
        __syncthreads();

        // S = q @ k^T  (16 rows x 64 cols per wave)
        f32x4 s_acc[4];
#pragma unroll
        for (int nt = 0; nt < 4; nt++) {
            int r = nt * 16 + l15;
            u16x8 b0 = *(const u16x8*)&lds_k[r * 64 + ((quad ^ (r & 7)) * 8)];
            u16x8 b1 = *(const u16x8*)&lds_k[r * 64 + (((quad + 4) ^ (r & 7)) * 8)];
            f32x4 c = {};
            c = mfma16(aq[0], b0, c);
            c = mfma16(aq[1], b1, c);
            s_acc[nt] = c;
        }

        // + rel+rpb (materialized, branch-free, coalesced)
#pragma unroll
        for (int nt = 0; nt < 4; nt++) {
            int jj = j0 + nt * 16 + l15;
#pragma unroll
            for (int reg = 0; reg < 4; reg++) {
                int ii = i0w + quad * 4 + reg;
                s_acc[nt][reg] += bf2f(bbase[((long)ii << 10) + jj]);
            }
        }

        // online softmax (rows at quad*4+reg, 16 lanes per row-group)
#pragma unroll
        for (int reg = 0; reg < 4; reg++) {
            float mx = fmaxf(fmaxf(s_acc[0][reg], s_acc[1][reg]), fmaxf(s_acc[2][reg], s_acc[3][reg]));
            for (int off = 1; off < 16; off <<= 1) mx = fmaxf(mx, __shfl_xor(mx, off, 64));
            float mnew = fmaxf(m_r[reg], mx);
            float alpha = __expf(m_r[reg] - mnew);
            float rs = 0.f;
#pragma unroll
            for (int nt = 0; nt < 4; nt++) {
                float p = __expf(s_acc[nt][reg] - mnew);
                s_acc[nt][reg] = p;
                rs += p;
            }
            for (int off = 1; off < 16; off <<= 1) rs += __shfl_xor(rs, off, 64);
            l_r[reg] = l_r[reg] * alpha + rs;
            m_r[reg] = mnew;
#pragma unroll
            for (int dt = 0; dt < 4; dt++) o_acc[dt][reg] *= alpha;
        }

        // P: C-layout -> LDS -> A-layout
#pragma unroll
        for (int nt = 0; nt < 4; nt++)
#pragma unroll
            for (int reg = 0; reg < 4; reg++)
                lds_p[wid][quad * 4 + reg][nt * 16 + l15] = f2bf(s_acc[nt][reg]);

        u16x8 pf0 = *(const u16x8*)&lds_p[wid][l15][quad * 8];
        u16x8 pf1 = *(const u16x8*)&lds_p[wid][l15][quad * 8 + 32];
#pragma unroll
        for (int dt = 0; dt < 4; dt++) {
            int r = dt * 16 + l15;
            u16x8 v0 = *(const u16x8*)&lds_v[r * 64 + ((quad ^ (r & 7)) * 8)];
            u16x8 v1 = *(const u16x8*)&lds_v[r * 64 + (((quad + 4) ^ (r & 7)) * 8)];
            o_acc[dt] = mfma16(pf0, v0, o_acc[dt]);
            o_acc[dt] = mfma16(pf1, v1, o_acc[dt]);
        }
    }

    int blk = (js * 32 + bh) * 16 + itile;
    float* PoB = Po + (long)blk * 4096;
#pragma unroll
    for (int dt = 0; dt < 4; dt++)
#pragma unroll
        for (int reg = 0; reg < 4; reg++) {
            int rr = wid * 16 + quad * 4 + reg;
            PoB[rr * 64 + dt * 16 + l15] = o_acc[dt][reg];
        }
    if (l15 == 0) {
#pragma unroll
        for (int reg = 0; reg < 4; reg++) {
            int rr = wid * 16 + quad * 4 + reg;
            Pm[blk * 64 + rr] = m_r[reg];
            Pl[blk * 64 + rr] = l_r[reg];
        }
    }
}

// ---------------- combine the 2 j-partials -> attn (bf16 [B,S,E]) -----------
__global__ __launch_bounds__(256) void combine_kernel(
    const float* __restrict__ Po, const float* __restrict__ Pm, const float* __restrict__ Pl,
    u16* __restrict__ attn)
{
    int itile = blockIdx.x, bh = blockIdx.y;
    int t = threadIdx.x;
    int c = t & 63, rg = t >> 6;
    int blk0 = bh * 16 + itile;
    int blk1 = (32 + bh) * 16 + itile;
    int b = bh >> 4, h = bh & 15;
    for (int rr = rg; rr < 64; rr += 4) {
        float m0 = Pm[blk0 * 64 + rr], m1 = Pm[blk1 * 64 + rr];
        float ms = fmaxf(m0, m1);
        float e0 = __expf(m0 - ms), e1 = __expf(m1 - ms);
        float l = Pl[blk0 * 64 + rr] * e0 + Pl[blk1 * 64 + rr] * e1;
        float o = Po[(long)blk0 * 4096 + rr * 64 + c] * e0
                + Po[(long)blk1 * 4096 + rr * 64 + c] * e1;
        int ii = itile * 64 + rr;
        attn[((long)(b * 1024 + ii)) * 1024 + h * 64 + c] = f2bf(o / l);
    }
}

// ---------------------------------------------------------------------------
extern "C" void kernel_launch(void* const* d_in, const int* in_sizes, int n_in,
                              void* d_out, int out_size, void* d_ws, size_t ws_size,
                              hipStream_t stream)
{
    const float* query = (const float*)d_in[0];
    const float* key_  = (const float*)d_in[1];
    const float* value = (const float*)d_in[2];
    const float* Wq = (const float*)d_in[3];
    const float* bq = (const float*)d_in[4];
    const float* Wk = (const float*)d_in[5];
    const float* bk = (const float*)d_in[6];
    const float* Wv = (const float*)d_in[7];
    const float* bv = (const float*)d_in[8];
    const float* Wo = (const float*)d_in[9];
    const float* bo = (const float*)d_in[10];
    const float* emb = (const float*)d_in[11];
    const float* rpb = (const float*)d_in[12];

    char* ws = (char*)d_ws;
    u16* xq   = (u16*)(ws + 0);          // 4 MB   (dead after QKV gemm)
    u16* xk   = (u16*)(ws + 4194304);    // 4 MB   (dead after QKV gemm)
    u16* xv   = (u16*)(ws + 8388608);    // 4 MB   (dead after QKV gemm)
    u16* WqT  = (u16*)(ws + 12582912);   // 2 MB   (dead after QKV gemm)
    u16* WkT  = (u16*)(ws + 14680064);   // 2 MB   (dead after QKV gemm)
    u16* WvT  = (u16*)(ws + 16777216);   // 2 MB   (dead after QKV gemm)
    u16* embb = (u16*)(ws + 18874368);   // 512 KB (dead after skew)
    u16* WoT  = (u16*)(ws + 19398656);   // 2 MB   (live till final gemm)
    u16* qb   = (u16*)(ws + 21495808);   // 4 MB   (dead after flash)
    u16* kb   = (u16*)(ws + 25690112);   // 4 MB
    u16* vT   = (u16*)(ws + 29884416);   // 4 MB
    u16* Brel2= (u16*)(ws + 34078720);   // 32768*1024*2 = 64 MB -> ends ~98.1 MB
    // overlays (regions dead by the time these are written):
    float* Po = (float*)(ws + 0);          // 16 MB over xq/xk/xv/WqT/WkT
    float* Pm = (float*)(ws + 16777216);   // 256 KB over WvT
    float* Pl = (float*)(ws + 17039360);   // 256 KB over WvT
    u16* attn = (u16*)(ws + 21495808);     // 4 MB over qb

    prep_kernel<<<7424, 256, 0, stream>>>(query, key_, value, emb, Wq, Wk, Wv, Wo,
                                          xq, xk, xv, embb, WqT, WkT, WvT, WoT);
    gemm_kernel<4><<<dim3(8, 16, 3), 256, 0, stream>>>(xq, xk, xv, WqT, WkT, WvT,
                                                       bq, bk, bv, qb, kb, vT, nullptr, 0);
    skew_kernel<<<2048, 256, 0, stream>>>(qb, embb, rpb, Brel2);
    flash_kernel<<<1024, 256, 0, stream>>>(qb, kb, vT, Brel2, Po, Pm, Pl);
    combine_kernel<<<dim3(16, 32), 256, 0, stream>>>(Po, Pm, Pl, attn);
    gemm_kernel<2><<<dim3(8, 32, 1), 256, 0, stream>>>(attn, nullptr, nullptr, WoT, nullptr, nullptr,
                                                       bo, nullptr, nullptr,
                                                       nullptr, nullptr, nullptr, (float*)d_out, 3);
}